// Round 1
// baseline (92.956 us; speedup 1.0000x reference)
//
#include <hip/hip_runtime.h>

// ---------------------------------------------------------------------------
// HeteroEdgeBias: bias[b, :, s, d] = edge_embedding[edge_type[e]]  (last edge
// index wins on duplicate (b,s,d), matching numpy fancy-assignment order).
//
// Pass 1: winner[b,s,d] = -1
// Pass 2: winner[b,s,d] = atomicMax(edge index) over edges hitting that cell
// Pass 3: dense emit: out[b,h,s,d] = winner>=0 ? emb[type[winner]][h] : 0
//         (single coalesced write of the whole 256 MiB output; no memset)
// ---------------------------------------------------------------------------

typedef float float4v __attribute__((ext_vector_type(4)));

__global__ void init_winner_kernel(int4* __restrict__ w4, int n4) {
    int i = blockIdx.x * blockDim.x + threadIdx.x;
    if (i < n4) w4[i] = make_int4(-1, -1, -1, -1);
}

__global__ void scatter_max_kernel(const int* __restrict__ ei,   // [2,E]
                                   const int* __restrict__ bv,   // [B*S]
                                   const int* __restrict__ gno,  // [B]
                                   int* __restrict__ w,          // [B*S*S]
                                   int E, int S) {
    int e = blockIdx.x * blockDim.x + threadIdx.x;
    if (e >= E) return;
    int src = ei[e];
    int dst = ei[E + e];
    int b   = bv[src];           // 32 KiB table, L1/L2 resident
    int off = gno[b];            // 64 B table
    int s   = src - off;
    int d   = dst - off;
    atomicMax(&w[(b * S + s) * S + d], e);   // device-scope, last-edge-wins
}

__global__ void emit_kernel(const int* __restrict__ w,     // [B*S*S]
                            const int* __restrict__ et,    // [E]
                            const float* __restrict__ emb, // [(T+1)*H]
                            float* __restrict__ out,       // [B,H,S,S]
                            int S, int H, int SS, int nemb, int n4) {
    extern __shared__ float s_emb[];
    for (int i = threadIdx.x; i < nemb; i += blockDim.x) s_emb[i] = emb[i];
    __syncthreads();

    int i4 = blockIdx.x * blockDim.x + threadIdx.x;
    if (i4 >= n4) return;

    int cell = i4 * 4;                 // linear index into (b, s, d)
    int b    = cell / SS;
    int rem  = cell - b * SS;          // s*S + d, multiple of 4 -> 16B aligned

    int4 win = ((const int4*)w)[i4];

    float* outb = out + (size_t)b * H * SS + rem;

    // all four cells empty: AND == -1 iff every component == -1
    if ((win.x & win.y & win.z & win.w) == -1) {
        float4v z = {0.f, 0.f, 0.f, 0.f};
        for (int h = 0; h < H; ++h)
            *(float4v*)(outb + (size_t)h * SS) = z;
        return;
    }

    int t0 = (win.x >= 0) ? et[win.x] : -1;
    int t1 = (win.y >= 0) ? et[win.y] : -1;
    int t2 = (win.z >= 0) ? et[win.z] : -1;
    int t3 = (win.w >= 0) ? et[win.w] : -1;

    for (int h = 0; h < H; ++h) {
        float4v v;
        v.x = (t0 >= 0) ? s_emb[t0 * H + h] : 0.f;
        v.y = (t1 >= 0) ? s_emb[t1 * H + h] : 0.f;
        v.z = (t2 >= 0) ? s_emb[t2 * H + h] : 0.f;
        v.w = (t3 >= 0) ? s_emb[t3 * H + h] : 0.f;
        *(float4v*)(outb + (size_t)h * SS) = v;
    }
}

extern "C" void kernel_launch(void* const* d_in, const int* in_sizes, int n_in,
                              void* d_out, int out_size, void* d_ws, size_t ws_size,
                              hipStream_t stream) {
    const int*   ei  = (const int*)d_in[0];   // edge_index [2,E]
    const int*   et  = (const int*)d_in[1];   // edge_type  [E]
    const int*   bv  = (const int*)d_in[2];   // batch_vec  [B*S]
    // d_in[3] = batch_size (device scalar, unused on host)
    // d_in[4] = max_seq_len (device scalar, unused on host)
    const int*   gno = (const int*)d_in[5];   // graph_node_offsets [B]
    const float* emb = (const float*)d_in[6]; // edge_embedding [(T+1)*H]
    float*       out = (float*)d_out;

    const int E    = in_sizes[0] / 2;
    const int B    = in_sizes[5];
    const int S    = in_sizes[2] / B;
    const int SS   = S * S;
    const int nemb = in_sizes[6];
    const int H    = out_size / (B * SS);

    int* w = (int*)d_ws;                      // [B*S*S] ints = 16 MiB
    const int ncell = B * SS;
    const int n4    = ncell / 4;

    const int BLK = 256;
    init_winner_kernel<<<(n4 + BLK - 1) / BLK, BLK, 0, stream>>>((int4*)w, n4);
    scatter_max_kernel<<<(E + BLK - 1) / BLK, BLK, 0, stream>>>(ei, bv, gno, w, E, S);
    emit_kernel<<<(n4 + BLK - 1) / BLK, BLK, nemb * sizeof(float), stream>>>(
        w, et, emb, out, S, H, SS, nemb, n4);
}

// Round 2
// 66.670 us; speedup vs baseline: 1.3943x; 1.3943x over previous
//
#include <hip/hip_runtime.h>

// ---------------------------------------------------------------------------
// HeteroEdgeBias: bias[b, :, s, d] = edge_embedding[edge_type[e]], last edge
// (highest e) wins on duplicate (b,s,d) -- numpy fancy-assignment semantics.
//
// Pass 1: winner[cell] = -1                      (16.8 MB write)
// Pass 2: winner[cell] = atomicMax((e<<5)|type)  (type packed in low 5 bits,
//                                                 e order preserved in high)
// Pass 3: dense emit, divergence-free:
//         block = 256 contiguous cells x all 16 heads.
//         wave0 decodes 64 winner-quads -> per-cell type byte in LDS
//         (t=17 => zero column), then 4 waves x 4 h-planes of full-width
//         1KB-coalesced float4 stores. No branches in the store path.
// ---------------------------------------------------------------------------

typedef float float4v __attribute__((ext_vector_type(4)));

__global__ void init_winner_kernel(int4* __restrict__ w4, int n4) {
    int stride = gridDim.x * blockDim.x;
    for (int i = blockIdx.x * blockDim.x + threadIdx.x; i < n4; i += stride)
        w4[i] = make_int4(-1, -1, -1, -1);
}

__global__ void scatter_max_kernel(const int* __restrict__ ei,   // [2,E]
                                   const int* __restrict__ et,   // [E]
                                   const int* __restrict__ bv,   // [B*S]
                                   const int* __restrict__ gno,  // [B]
                                   int* __restrict__ w,          // [B*S*S]
                                   int E, int S) {
    int e = blockIdx.x * blockDim.x + threadIdx.x;
    if (e >= E) return;
    int src = ei[e];            // coalesced
    int dst = ei[E + e];        // coalesced
    int ty  = et[e];            // coalesced
    int b   = bv[src];          // 32 KiB table, cache-resident
    int off = gno[b];           // 64 B table
    int s   = src - off;
    int d   = dst - off;
    atomicMax(&w[(b * S + s) * S + d], (e << 5) | ty);  // last-edge-wins
}

// Specialized H==16 emit: block covers 256 cells (all within one b since
// SS % 256 == 0), emits 256 cells x 16 heads = 16 KB of output per block.
__global__ __launch_bounds__(256) void emit16_kernel(
        const int* __restrict__ w,      // [B*S*S] packed winners
        const float* __restrict__ emb,  // [(T+1)*16]
        float* __restrict__ out,        // [B,16,S,S]
        int SS, int nT) {               // nT = T+1 (<= 17)
    __shared__ float    s_emb[16 * 18];   // [h][t], t=17 column is zeros
    __shared__ unsigned s_ty[64];         // 4 packed type bytes per quad

    int tid = threadIdx.x;
    for (int i = tid; i < 16 * 18; i += 256) {
        int h = i / 18, t = i - h * 18;
        s_emb[i] = (t < nT) ? emb[t * 16 + h] : 0.f;
    }

    int cellbase = blockIdx.x << 8;       // 256 cells per block
    int b   = cellbase / SS;              // uniform (SS multiple of 256)
    int rem = cellbase - b * SS;

    if (tid < 64) {
        int4 win = ((const int4*)w)[(cellbase >> 2) + tid];
        unsigned t0 = (win.x >= 0) ? (unsigned)(win.x & 31) : 17u;
        unsigned t1 = (win.y >= 0) ? (unsigned)(win.y & 31) : 17u;
        unsigned t2 = (win.z >= 0) ? (unsigned)(win.z & 31) : 17u;
        unsigned t3 = (win.w >= 0) ? (unsigned)(win.w & 31) : 17u;
        s_ty[tid] = t0 | (t1 << 8) | (t2 << 16) | (t3 << 24);
    }
    __syncthreads();

    int lane = tid & 63;
    int wg   = tid >> 6;                  // 0..3, uniform per wave
    unsigned u = s_ty[lane];              // conflict-free (word == lane)
    int t0 =  u        & 255;
    int t1 = (u >> 8)  & 255;
    int t2 = (u >> 16) & 255;
    int t3 =  u >> 24;

    float* base = out + (size_t)(b * 16) * SS + rem + lane * 4;
#pragma unroll
    for (int i = 0; i < 4; ++i) {
        int h = wg * 4 + i;               // uniform per wave per iter
        const float* eh = s_emb + h * 18; // 18 consecutive words: no conflicts
        float4v v = { eh[t0], eh[t1], eh[t2], eh[t3] };
        *(float4v*)(base + (size_t)h * SS) = v;   // 64 lanes x 16B = 1KB
    }
}

// Generic fallback (any H / alignment) -- the round-1 emit.
__global__ void emit_generic_kernel(const int* __restrict__ w,
                                    const float* __restrict__ emb,
                                    float* __restrict__ out,
                                    int H, int SS, int nemb, int n4) {
    extern __shared__ float s_emb[];
    for (int i = threadIdx.x; i < nemb; i += blockDim.x) s_emb[i] = emb[i];
    __syncthreads();

    int i4 = blockIdx.x * blockDim.x + threadIdx.x;
    if (i4 >= n4) return;
    int cell = i4 * 4;
    int b    = cell / SS;
    int rem  = cell - b * SS;
    int4 win = ((const int4*)w)[i4];
    float* outb = out + (size_t)b * H * SS + rem;

    int t0 = (win.x >= 0) ? (win.x & 31) : -1;
    int t1 = (win.y >= 0) ? (win.y & 31) : -1;
    int t2 = (win.z >= 0) ? (win.z & 31) : -1;
    int t3 = (win.w >= 0) ? (win.w & 31) : -1;
    for (int h = 0; h < H; ++h) {
        float4v v;
        v.x = (t0 >= 0) ? s_emb[t0 * H + h] : 0.f;
        v.y = (t1 >= 0) ? s_emb[t1 * H + h] : 0.f;
        v.z = (t2 >= 0) ? s_emb[t2 * H + h] : 0.f;
        v.w = (t3 >= 0) ? s_emb[t3 * H + h] : 0.f;
        *(float4v*)(outb + (size_t)h * SS) = v;
    }
}

extern "C" void kernel_launch(void* const* d_in, const int* in_sizes, int n_in,
                              void* d_out, int out_size, void* d_ws, size_t ws_size,
                              hipStream_t stream) {
    const int*   ei  = (const int*)d_in[0];   // edge_index [2,E]
    const int*   et  = (const int*)d_in[1];   // edge_type  [E]
    const int*   bv  = (const int*)d_in[2];   // batch_vec  [B*S]
    const int*   gno = (const int*)d_in[5];   // graph_node_offsets [B]
    const float* emb = (const float*)d_in[6]; // edge_embedding [(T+1)*H]
    float*       out = (float*)d_out;

    const int E    = in_sizes[0] / 2;
    const int B    = in_sizes[5];
    const int S    = in_sizes[2] / B;
    const int SS   = S * S;
    const int nemb = in_sizes[6];
    const int H    = out_size / (B * SS);
    const int nT   = nemb / H;                // T+1

    int* w = (int*)d_ws;                      // [B*S*S] ints
    const int ncell = B * SS;
    const int n4    = ncell / 4;

    const int BLK = 256;
    init_winner_kernel<<<2048, BLK, 0, stream>>>((int4*)w, n4);
    scatter_max_kernel<<<(E + BLK - 1) / BLK, BLK, 0, stream>>>(
        ei, et, bv, gno, w, E, S);

    if (H == 16 && (SS & 255) == 0 && nT <= 17) {
        emit16_kernel<<<ncell / 256, BLK, 0, stream>>>(w, emb, out, SS, nT);
    } else {
        emit_generic_kernel<<<(n4 + BLK - 1) / BLK, BLK,
                              nemb * sizeof(float), stream>>>(
            w, emb, out, H, SS, nemb, n4);
    }
}

// Round 3
// 62.463 us; speedup vs baseline: 1.4882x; 1.0674x over previous
//
#include <hip/hip_runtime.h>

// ---------------------------------------------------------------------------
// HeteroEdgeBias: bias[b, :, s, d] = edge_embedding[edge_type[e]], last edge
// (highest e) wins on duplicate (b,s,d) -- numpy fancy-assignment semantics.
//
// Row-binned plan (specialized: S=512, H=16, nT<=17, E<=2^18):
//   A) zero 8192 per-row counters (32 KB)
//   B) bin: per edge, rec = (e<<14)|(d<<5)|ty appended to its (b,s) row bin
//      (atomicAdd on hot L2-resident counters; ~1 MB of bin writes)
//   C) emit: one block per row: replay bin into a 2 KB LDS winner row via
//      LDS atomicMax((e+1)<<5|ty) -- deterministic max-reduce -- then write
//      512 cells x 16 heads = 32 KB of coalesced branch-free float4 stores.
// The 16.8 MB HBM winner array (init write + random atomics + re-read) from
// the previous version is eliminated entirely.
// ---------------------------------------------------------------------------

typedef float float4v __attribute__((ext_vector_type(4)));

#define CAP 128   // bin capacity per row; edges/row ~ Poisson(32)

__global__ void zero_cnt_kernel(int* __restrict__ cnt, int n) {
    int i = blockIdx.x * blockDim.x + threadIdx.x;
    if (i < n) cnt[i] = 0;
}

__global__ void bin_kernel(const int* __restrict__ ei,   // [2,E]
                           const int* __restrict__ et,   // [E]
                           const int* __restrict__ bv,   // [B*S]
                           const int* __restrict__ gno,  // [B]
                           int* __restrict__ cnt,        // [B*S]
                           unsigned* __restrict__ bins,  // [B*S*CAP]
                           int E, int S) {
    int e = blockIdx.x * blockDim.x + threadIdx.x;
    if (e >= E) return;
    int src = ei[e];            // coalesced
    int dst = ei[E + e];        // coalesced
    int ty  = et[e];            // coalesced
    int b   = bv[src];          // 32 KiB table, cache-resident
    int off = gno[b];           // 64 B table
    int s   = src - off;
    int d   = dst - off;
    int row = b * S + s;
    int slot = atomicAdd(&cnt[row], 1);
    if (slot < CAP)
        bins[(size_t)row * CAP + slot] =
            ((unsigned)e << 14) | ((unsigned)d << 5) | (unsigned)ty;
}

// One block per (b,s) row. S=512, H=16.
__global__ __launch_bounds__(256) void emit_row_kernel(
        const int* __restrict__ cnt,        // [nrows]
        const unsigned* __restrict__ bins,  // [nrows*CAP]
        const float* __restrict__ emb,      // [nT*16]
        float* __restrict__ out,            // [B,16,512,512]
        int nT) {
    __shared__ float s_emb[16 * 18];   // [h][t], t=17 column is zeros
    __shared__ int   win[512];

    int tid = threadIdx.x;
    for (int i = tid; i < 16 * 18; i += 256) {
        int h = i / 18, t = i - h * 18;
        s_emb[i] = (t < nT) ? emb[t * 16 + h] : 0.f;
    }
    win[tid]       = 0;
    win[tid + 256] = 0;
    __syncthreads();

    int row = blockIdx.x;
    int n = cnt[row];
    if (n > CAP) n = CAP;
    const unsigned* bb = bins + (size_t)row * CAP;
    for (int i = tid; i < n; i += 256) {
        unsigned rec = bb[i];
        int d   = (rec >> 5) & 511;
        int val = (int)((((rec >> 14) + 1u) << 5) | (rec & 31u));
        atomicMax(&win[d], val);           // LDS atomic, last-edge-wins
    }
    __syncthreads();

    // thread -> quad q (0..127), half h0 (0..1); planes h = h0*8 + i
    int q  = tid & 127;
    int h0 = tid >> 7;
    int w0 = win[4 * q + 0], w1 = win[4 * q + 1];
    int w2 = win[4 * q + 2], w3 = win[4 * q + 3];
    int t0 = w0 ? (w0 & 31) : 17;
    int t1 = w1 ? (w1 & 31) : 17;
    int t2 = w2 ? (w2 & 31) : 17;
    int t3 = w3 ? (w3 & 31) : 17;

    int b = row >> 9;
    int s = row & 511;
    // out[b][h][s][d]: plane stride 2^18 floats
    float* base = out + ((size_t)(b * 16) << 18) + (s << 9) + (q << 2);
#pragma unroll
    for (int i = 0; i < 8; ++i) {
        int h = h0 * 8 + i;                 // wave-uniform
        const float* eh = s_emb + h * 18;   // 18 consecutive words: no conflicts
        float4v v = { eh[t0], eh[t1], eh[t2], eh[t3] };
        *(float4v*)(base + ((size_t)h << 18)) = v;   // 64 lanes x 16B = 1KB
    }
}

// ------------------------- generic fallback path ---------------------------

__global__ void init_winner_kernel(int4* __restrict__ w4, int n4) {
    int stride = gridDim.x * blockDim.x;
    for (int i = blockIdx.x * blockDim.x + threadIdx.x; i < n4; i += stride)
        w4[i] = make_int4(-1, -1, -1, -1);
}

__global__ void scatter_max_kernel(const int* __restrict__ ei,
                                   const int* __restrict__ et,
                                   const int* __restrict__ bv,
                                   const int* __restrict__ gno,
                                   int* __restrict__ w,
                                   int E, int S) {
    int e = blockIdx.x * blockDim.x + threadIdx.x;
    if (e >= E) return;
    int src = ei[e];
    int dst = ei[E + e];
    int ty  = et[e];
    int b   = bv[src];
    int off = gno[b];
    int s   = src - off;
    int d   = dst - off;
    atomicMax(&w[(b * S + s) * S + d], (e << 5) | ty);
}

__global__ void emit_generic_kernel(const int* __restrict__ w,
                                    const float* __restrict__ emb,
                                    float* __restrict__ out,
                                    int H, int SS, int nemb, int n4) {
    extern __shared__ float s_emb[];
    for (int i = threadIdx.x; i < nemb; i += blockDim.x) s_emb[i] = emb[i];
    __syncthreads();

    int i4 = blockIdx.x * blockDim.x + threadIdx.x;
    if (i4 >= n4) return;
    int cell = i4 * 4;
    int b    = cell / SS;
    int rem  = cell - b * SS;
    int4 win = ((const int4*)w)[i4];
    float* outb = out + (size_t)b * H * SS + rem;

    int t0 = (win.x >= 0) ? (win.x & 31) : -1;
    int t1 = (win.y >= 0) ? (win.y & 31) : -1;
    int t2 = (win.z >= 0) ? (win.z & 31) : -1;
    int t3 = (win.w >= 0) ? (win.w & 31) : -1;
    for (int h = 0; h < H; ++h) {
        float4v v;
        v.x = (t0 >= 0) ? s_emb[t0 * H + h] : 0.f;
        v.y = (t1 >= 0) ? s_emb[t1 * H + h] : 0.f;
        v.z = (t2 >= 0) ? s_emb[t2 * H + h] : 0.f;
        v.w = (t3 >= 0) ? s_emb[t3 * H + h] : 0.f;
        *(float4v*)(outb + (size_t)h * SS) = v;
    }
}

// ---------------------------------------------------------------------------

extern "C" void kernel_launch(void* const* d_in, const int* in_sizes, int n_in,
                              void* d_out, int out_size, void* d_ws, size_t ws_size,
                              hipStream_t stream) {
    const int*   ei  = (const int*)d_in[0];   // edge_index [2,E]
    const int*   et  = (const int*)d_in[1];   // edge_type  [E]
    const int*   bv  = (const int*)d_in[2];   // batch_vec  [B*S]
    const int*   gno = (const int*)d_in[5];   // graph_node_offsets [B]
    const float* emb = (const float*)d_in[6]; // edge_embedding [(T+1)*H]
    float*       out = (float*)d_out;

    const int E    = in_sizes[0] / 2;
    const int B    = in_sizes[5];
    const int S    = in_sizes[2] / B;
    const int SS   = S * S;
    const int nemb = in_sizes[6];
    const int H    = out_size / (B * SS);
    const int nT   = nemb / H;                // T+1
    const int nrows = B * S;

    const int BLK = 256;

    const size_t need = (size_t)nrows * sizeof(int)
                      + (size_t)nrows * CAP * sizeof(unsigned);

    if (H == 16 && S == 512 && nT <= 17 && E <= (1 << 18) && ws_size >= need) {
        int*      cnt  = (int*)d_ws;                       // [nrows] = 32 KB
        unsigned* bins = (unsigned*)((char*)d_ws + (size_t)nrows * sizeof(int));

        zero_cnt_kernel<<<(nrows + BLK - 1) / BLK, BLK, 0, stream>>>(cnt, nrows);
        bin_kernel<<<(E + BLK - 1) / BLK, BLK, 0, stream>>>(
            ei, et, bv, gno, cnt, bins, E, S);
        emit_row_kernel<<<nrows, BLK, 0, stream>>>(cnt, bins, emb, out, nT);
    } else {
        // generic 3-pass fallback (HBM winner array)
        int* w = (int*)d_ws;
        const int ncell = B * SS;
        const int n4    = ncell / 4;
        init_winner_kernel<<<2048, BLK, 0, stream>>>((int4*)w, n4);
        scatter_max_kernel<<<(E + BLK - 1) / BLK, BLK, 0, stream>>>(
            ei, et, bv, gno, w, E, S);
        emit_generic_kernel<<<(n4 + BLK - 1) / BLK, BLK,
                              nemb * sizeof(float), stream>>>(
            w, emb, out, H, SS, nemb, n4);
    }
}